// Round 1
// baseline (317.513 us; speedup 1.0000x reference)
//
#include <hip/hip_runtime.h>
#include <math.h>

#define BN 1024
#define SN 64
#define DN 256
#define CHN 1024
#define GRP 32

__device__ __forceinline__ float gelu_exact(float x) {
    return 0.5f * x * (1.0f + erff(x * 0.70710678118654752440f));
}

// K1: scene logits + log_softmax + argmax + pose-bias init + scene binning.
// One block per sample b, 256 thr = 4 waves.
__global__ __launch_bounds__(256, 4) void k_scene(
    const float* __restrict__ dt, const float* __restrict__ dr,
    const float* __restrict__ Wsc, const float* __restrict__ bsc,
    const float* __restrict__ bt_o, const float* __restrict__ br_o,
    float* __restrict__ out_logd, float* __restrict__ pose,
    int* __restrict__ counts, int* __restrict__ lists)
{
    int b = blockIdx.x;
    int tid = threadIdx.x;
    int lane = tid & 63;
    int wave = tid >> 6;
    __shared__ float part[SN][65];   // +1 pad: reduction read is 2-way (free)
    __shared__ float logits[SN];

    float4 wt = *(const float4*)&Wsc[4 * lane];
    float4 wr = *(const float4*)&Wsc[DN + 4 * lane];
    const float* pt = dt + (size_t)b * SN * DN + 4 * lane;
    const float* pr = dr + (size_t)b * SN * DN + 4 * lane;
    float bias0 = bsc[0];

    float p[16];
    #pragma unroll 8
    for (int k = 0; k < 16; k++) {
        int s = wave * 16 + k;          // each wave streams a contiguous 16KB chunk
        float4 t4 = *(const float4*)&pt[s * DN];
        float4 r4 = *(const float4*)&pr[s * DN];
        p[k] = t4.x * wt.x + t4.y * wt.y + t4.z * wt.z + t4.w * wt.w
             + r4.x * wr.x + r4.y * wr.y + r4.z * wr.z + r4.w * wr.w;
    }
    #pragma unroll
    for (int k = 0; k < 16; k++) part[wave * 16 + k][lane] = p[k];
    __syncthreads();

    {
        int s = tid >> 2, q = tid & 3;
        float sum = 0.f;
        #pragma unroll
        for (int j = 0; j < 16; j++) sum += part[s][q * 16 + j];
        sum += __shfl_xor(sum, 1);
        sum += __shfl_xor(sum, 2);
        if (q == 0) logits[s] = sum + bias0;
    }
    __syncthreads();

    if (wave == 0) {
        float l = logits[lane];
        float m = l; int idx = lane;
        #pragma unroll
        for (int off = 32; off >= 1; off >>= 1) {
            float om = __shfl_xor(m, off);
            int oidx = __shfl_xor(idx, off);
            if (om > m || (om == m && oidx < idx)) { m = om; idx = oidx; }
        }
        float e = expf(l - m);
        float ssum = e;
        #pragma unroll
        for (int off = 32; off >= 1; off >>= 1) ssum += __shfl_xor(ssum, off);
        float logZ = m + logf(ssum);
        out_logd[b * SN + lane] = l - logZ;
        // fused prep: bin this sample + write pose output biases
        if (lane == 0) {
            int pos = atomicAdd(&counts[idx], 1);
            lists[idx * BN + pos] = b;
        }
        if (lane < 7)
            pose[b * 7 + lane] = (lane < 3) ? bt_o[idx * 3 + lane]
                                            : br_o[idx * 4 + (lane - 3)];
    }
}

// K2 v2: expert MLP heads, latency-hiding rework.
//  - GRP=32: one group covers a typical scene -> logical weight traffic
//    drops from ~186MB (ceil(cnt/16) groups) to ~132MB (ceil(cnt/32)).
//  - item = (scene-group, type z, 128-col chunk): 16 blocks/group
//    (2 types x 8 chunks) -> ~1056 active blocks vs ~745 -> occupancy up.
//  - within-block D-split: 256 thr = 128 cols x 2 row-halves (dh = tid>>7);
//    partial sums combined through LDS (reusing g's storage) at the end.
//  - double-buffered weight prefetch (wa/wb): next 8 rows are issued before
//    computing the current 8 -> ~8-16 loads in flight per wave continuously
//    instead of a load->waitcnt->compute stall each step.
// ALL acc[] accesses remain constant-indexed so acc lives in VGPRs.
__global__ __launch_bounds__(256, 4) void k_expert(
    const float* __restrict__ dt, const float* __restrict__ dr,
    const float* __restrict__ Wt_h, const float* __restrict__ bt_h, const float* __restrict__ Wt_o,
    const float* __restrict__ Wr_h, const float* __restrict__ br_h, const float* __restrict__ Wr_o,
    const int* __restrict__ counts, const int* __restrict__ lists,
    float* __restrict__ pose)
{
    __shared__ float g[GRP][DN];     // 32 KB gathered descriptors (full rows)
    __shared__ int pref[SN + 1];
    __shared__ int bl[GRP];
    int tid = threadIdx.x;
    int lane = tid & 63;
    int wavei = tid >> 6;

    // group-count prefix scan (wave 0)
    if (wavei == 0) {
        int c = counts[lane];
        int ng = (c + GRP - 1) >> 5;
        #pragma unroll
        for (int off = 1; off < 64; off <<= 1) {
            int v = __shfl_up(ng, off);
            if (lane >= off) ng += v;
        }
        pref[lane + 1] = ng;
        if (lane == 0) pref[0] = 0;
    }
    __syncthreads();

    int q = blockIdx.x;
    if (q >= pref[SN] * 16) return;  // uniform exit

    int s = 0;
    while (pref[s + 1] * 16 <= q) s++;
    int r = q - pref[s] * 16;
    int grp = r >> 4;                // group of up to 32 samples
    int z = (r >> 3) & 1;            // head type (t / rot)
    int chunk = r & 7;               // 128-col chunk of CH

    int cnt = counts[s];
    int base = grp * GRP;
    int n = min(GRP, cnt - base);

    int col = tid & 127;             // column within chunk
    int dh = tid >> 7;               // row half: 0 -> rows 0..127, 1 -> 128..255
    int h0 = (chunk << 7) + col;     // hidden unit index

    const float* Wh; const float* bh; const float* Wo; const float* descs; int no, ob;
    if (z == 0) {
        Wh = Wt_h + (size_t)s * DN * CHN; bh = bt_h + s * CHN;
        Wo = Wt_o + (size_t)s * CHN * 3;  descs = dt; no = 3; ob = 0;
    } else {
        Wh = Wr_h + (size_t)s * DN * CHN; bh = br_h + s * CHN;
        Wo = Wr_o + (size_t)s * CHN * 4;  descs = dr; no = 4; ob = 3;
    }

    // gather: 32 rows x 256 floats, float4-vectorized, one row per wave/iter
    #pragma unroll 2
    for (int ii = 0; ii < 8; ii++) {
        int i = ii * 4 + wavei;
        int bi = 0;
        float4 v = make_float4(0.f, 0.f, 0.f, 0.f);
        if (i < n) {
            bi = lists[s * BN + base + i];
            v = *(const float4*)&descs[(size_t)bi * SN * DN + s * DN + 4 * lane];
        }
        *(float4*)&g[i][4 * lane] = v;
        if (lane == 0) bl[i] = bi;
    }
    __syncthreads();

    int d0 = dh << 7;                // this thread's row-half base
    const float* wp = Wh + (size_t)d0 * CHN + h0;

    float acc[GRP];
    #pragma unroll
    for (int i = 0; i < GRP; i++) acc[i] = 0.f;

    float wa[8], wb[8];
    #pragma unroll
    for (int rr = 0; rr < 8; rr++) wa[rr] = wp[(size_t)rr * CHN];

    auto compute = [&](const float (&w)[8], int db) {
        #pragma unroll
        for (int i = 0; i < GRP; i++) {
            float4 ga = *(const float4*)&g[i][d0 + db];      // broadcast ds_read_b128
            float4 gb = *(const float4*)&g[i][d0 + db + 4];
            acc[i] += ga.x * w[0] + ga.y * w[1] + ga.z * w[2] + ga.w * w[3]
                    + gb.x * w[4] + gb.y * w[5] + gb.z * w[6] + gb.w * w[7];
        }
    };

    // software-pipelined over 128 rows: issue next 8 loads, compute current 8
    for (int db = 0; db < 112; db += 16) {
        #pragma unroll
        for (int rr = 0; rr < 8; rr++) wb[rr] = wp[(size_t)(db + 8 + rr) * CHN];
        compute(wa, db);
        #pragma unroll
        for (int rr = 0; rr < 8; rr++) wa[rr] = wp[(size_t)(db + 16 + rr) * CHN];
        compute(wb, db + 8);
    }
    #pragma unroll
    for (int rr = 0; rr < 8; rr++) wb[rr] = wp[(size_t)(120 + rr) * CHN];
    compute(wa, 112);
    compute(wb, 120);

    // combine row-halves through LDS (reuse g's storage; main loop done with g)
    __syncthreads();
    float* comb = &g[0][0];          // viewed as [GRP][128]
    if (dh == 1) {
        #pragma unroll
        for (int i = 0; i < GRP; i++) comb[i * 128 + col] = acc[i];
    }
    __syncthreads();
    if (dh == 1) return;             // upper half done (after final barrier)
    #pragma unroll
    for (int i = 0; i < GRP; i++) acc[i] += comb[i * 128 + col];

    float hb = bh[h0];
    float wo[4];
    #pragma unroll
    for (int o = 0; o < 4; o++) wo[o] = (o < no) ? Wo[h0 * no + o] : 0.f;

    // epilogue: waves 0-1 (cols 0..127); compile-time trip count + predication
    #pragma unroll
    for (int i = 0; i < GRP; i++) {
        if (i < n) {
            float hv = gelu_exact(acc[i] + hb);
            #pragma unroll
            for (int o = 0; o < 4; o++) {
                if (o < no) {
                    float p = hv * wo[o];
                    #pragma unroll
                    for (int off = 32; off >= 1; off >>= 1) p += __shfl_down(p, off);
                    if (lane == 0) atomicAdd(&pose[bl[i] * 7 + ob + o], p);
                }
            }
        }
    }
}

extern "C" void kernel_launch(void* const* d_in, const int* in_sizes, int n_in,
                              void* d_out, int out_size, void* d_ws, size_t ws_size,
                              hipStream_t stream) {
    const float* dt    = (const float*)d_in[0];
    const float* dr    = (const float*)d_in[1];
    const float* Wsc   = (const float*)d_in[2];
    const float* bsc   = (const float*)d_in[3];
    const float* Wt_h  = (const float*)d_in[4];
    const float* bt_h  = (const float*)d_in[5];
    const float* Wt_o  = (const float*)d_in[6];
    const float* bt_o  = (const float*)d_in[7];
    const float* Wr_h  = (const float*)d_in[8];
    const float* br_h  = (const float*)d_in[9];
    const float* Wr_o  = (const float*)d_in[10];
    const float* br_o  = (const float*)d_in[11];

    float* pose = (float*)d_out;                    // [B,7]
    float* logd = (float*)d_out + BN * 7;           // [B,S]

    int* counts  = (int*)((char*)d_ws + 4096);              // 256 B
    int* lists   = (int*)((char*)d_ws + 8192);              // 256 KB

    hipMemsetAsync(counts, 0, SN * sizeof(int), stream);

    k_scene<<<BN, 256, 0, stream>>>(dt, dr, Wsc, bsc, bt_o, br_o,
                                    logd, pose, counts, lists);
    // max groups = sum ceil(cnt/32) <= (1024 + 64*31)/32 = 94; 94*16 = 1504
    k_expert<<<1536, 256, 0, stream>>>(
        dt, dr, Wt_h, bt_h, Wt_o, Wr_h, br_h, Wr_o, counts, lists, pose);
}

// Round 2
// 310.672 us; speedup vs baseline: 1.0220x; 1.0220x over previous
//
#include <hip/hip_runtime.h>
#include <math.h>

#define BN 1024
#define SN 64
#define DN 256
#define CHN 1024
#define GRP 16

__device__ __forceinline__ float gelu_exact(float x) {
    return 0.5f * x * (1.0f + erff(x * 0.70710678118654752440f));
}

// K1: scene logits + log_softmax + argmax + pose-bias init + scene binning.
// One block per sample b, 256 thr = 4 waves. (unchanged from proven baseline)
__global__ __launch_bounds__(256, 4) void k_scene(
    const float* __restrict__ dt, const float* __restrict__ dr,
    const float* __restrict__ Wsc, const float* __restrict__ bsc,
    const float* __restrict__ bt_o, const float* __restrict__ br_o,
    float* __restrict__ out_logd, float* __restrict__ pose,
    int* __restrict__ counts, int* __restrict__ lists)
{
    int b = blockIdx.x;
    int tid = threadIdx.x;
    int lane = tid & 63;
    int wave = tid >> 6;
    __shared__ float part[SN][65];   // +1 pad: reduction read is 2-way (free)
    __shared__ float logits[SN];

    float4 wt = *(const float4*)&Wsc[4 * lane];
    float4 wr = *(const float4*)&Wsc[DN + 4 * lane];
    const float* pt = dt + (size_t)b * SN * DN + 4 * lane;
    const float* pr = dr + (size_t)b * SN * DN + 4 * lane;
    float bias0 = bsc[0];

    float p[16];
    #pragma unroll 8
    for (int k = 0; k < 16; k++) {
        int s = wave * 16 + k;          // each wave streams a contiguous 16KB chunk
        float4 t4 = *(const float4*)&pt[s * DN];
        float4 r4 = *(const float4*)&pr[s * DN];
        p[k] = t4.x * wt.x + t4.y * wt.y + t4.z * wt.z + t4.w * wt.w
             + r4.x * wr.x + r4.y * wr.y + r4.z * wr.z + r4.w * wr.w;
    }
    #pragma unroll
    for (int k = 0; k < 16; k++) part[wave * 16 + k][lane] = p[k];
    __syncthreads();

    {
        int s = tid >> 2, q = tid & 3;
        float sum = 0.f;
        #pragma unroll
        for (int j = 0; j < 16; j++) sum += part[s][q * 16 + j];
        sum += __shfl_xor(sum, 1);
        sum += __shfl_xor(sum, 2);
        if (q == 0) logits[s] = sum + bias0;
    }
    __syncthreads();

    if (wave == 0) {
        float l = logits[lane];
        float m = l; int idx = lane;
        #pragma unroll
        for (int off = 32; off >= 1; off >>= 1) {
            float om = __shfl_xor(m, off);
            int oidx = __shfl_xor(idx, off);
            if (om > m || (om == m && oidx < idx)) { m = om; idx = oidx; }
        }
        float e = expf(l - m);
        float ssum = e;
        #pragma unroll
        for (int off = 32; off >= 1; off >>= 1) ssum += __shfl_xor(ssum, off);
        float logZ = m + logf(ssum);
        out_logd[b * SN + lane] = l - logZ;
        // fused prep: bin this sample + write pose output biases
        if (lane == 0) {
            int pos = atomicAdd(&counts[idx], 1);
            lists[idx * BN + pos] = b;
        }
        if (lane < 7)
            pose[b * 7 + lane] = (lane < 3) ? bt_o[idx * 3 + lane]
                                            : br_o[idx * 4 + (lane - 3)];
    }
}

// K2 v3: concurrency rework, keeping v1's proven per-block economics.
//  - GRP=16 (16 KB gather LDS -> 9-block LDS residency ceiling, 12.5% gather
//    overhead vs weights -- v2's GRP=32 had 25% overhead + 4-block ceiling).
//  - item = (group, type z, 128-col chunk): 16 items/group -> ~1488 working
//    blocks (2x v1's 745) -> target ~6 blocks/CU resident, ~24 waves/CU.
//  - within-block 2-way D-split (dh = tid>>7), partials combined via LDS
//    (verified-correct v2 mechanism).
//  - w[16] weight batch per step: 4 KB in flight per wave per step; VGPR
//    budget capped at 85 via __launch_bounds__(256,6).
// ALL acc[] accesses constant-indexed -> VGPRs, not scratch.
__global__ __launch_bounds__(256, 6) void k_expert(
    const float* __restrict__ dt, const float* __restrict__ dr,
    const float* __restrict__ Wt_h, const float* __restrict__ bt_h, const float* __restrict__ Wt_o,
    const float* __restrict__ Wr_h, const float* __restrict__ br_h, const float* __restrict__ Wr_o,
    const int* __restrict__ counts, const int* __restrict__ lists,
    float* __restrict__ pose)
{
    __shared__ float g[GRP][DN];     // 16 KB gathered descriptors
    __shared__ int pref[SN + 1];
    __shared__ int bl[GRP];
    int tid = threadIdx.x;
    int lane = tid & 63;

    // group-count prefix scan (wave 0)
    if (tid < 64) {
        int c = counts[lane];
        int ng = (c + GRP - 1) >> 4;
        #pragma unroll
        for (int off = 1; off < 64; off <<= 1) {
            int v = __shfl_up(ng, off);
            if (lane >= off) ng += v;
        }
        pref[lane + 1] = ng;
        if (lane == 0) pref[0] = 0;
    }
    __syncthreads();

    int q = blockIdx.x;
    if (q >= pref[SN] * 16) return;  // uniform exit

    int s = 0;
    while (pref[s + 1] * 16 <= q) s++;
    int r = q - pref[s] * 16;
    int grp = r >> 4;                // group of up to 16 samples
    int z = (r >> 3) & 1;            // head type (t / rot)
    int chunk = r & 7;               // 128-col chunk of CH

    int cnt = counts[s];
    int base = grp * GRP;
    int n = min(GRP, cnt - base);

    const float* Wh; const float* bh; const float* Wo; const float* descs; int no, ob;
    if (z == 0) {
        Wh = Wt_h + (size_t)s * DN * CHN; bh = bt_h + s * CHN;
        Wo = Wt_o + (size_t)s * CHN * 3;  descs = dt; no = 3; ob = 0;
    } else {
        Wh = Wr_h + (size_t)s * DN * CHN; bh = br_h + s * CHN;
        Wo = Wr_o + (size_t)s * CHN * 4;  descs = dr; no = 4; ob = 3;
    }

    // gather: 16 rows x 256 floats, one row per 256-thread pass (coalesced)
    #pragma unroll 4
    for (int i = 0; i < GRP; i++) {
        int bi = 0; float v = 0.f;
        if (i < n) {
            bi = lists[s * BN + base + i];
            v = descs[(size_t)bi * SN * DN + s * DN + tid];
        }
        g[i][tid] = v;
        if (tid == 0) bl[i] = bi;
    }
    __syncthreads();

    int col = tid & 127;             // column within chunk
    int dh = tid >> 7;               // row half: 0 -> rows 0..127, 1 -> 128..255
    int d0 = dh << 7;
    int h0 = (chunk << 7) + col;     // hidden unit index
    const float* wp = Wh + (size_t)d0 * CHN + h0;

    float acc[GRP];
    #pragma unroll
    for (int i = 0; i < GRP; i++) acc[i] = 0.f;

    // 8 steps of 16 rows: 16 loads (4 KB/wave) issued per step, then 256 FMA
    for (int db = 0; db < 128; db += 16) {
        float w[16];
        #pragma unroll
        for (int rr = 0; rr < 16; rr++) w[rr] = wp[(size_t)(db + rr) * CHN];
        #pragma unroll
        for (int i = 0; i < GRP; i++) {
            float4 a0 = *(const float4*)&g[i][d0 + db];      // broadcast ds_read_b128
            float4 a1 = *(const float4*)&g[i][d0 + db + 4];
            float4 a2 = *(const float4*)&g[i][d0 + db + 8];
            float4 a3 = *(const float4*)&g[i][d0 + db + 12];
            acc[i] += a0.x * w[0]  + a0.y * w[1]  + a0.z * w[2]  + a0.w * w[3]
                    + a1.x * w[4]  + a1.y * w[5]  + a1.z * w[6]  + a1.w * w[7]
                    + a2.x * w[8]  + a2.y * w[9]  + a2.z * w[10] + a2.w * w[11]
                    + a3.x * w[12] + a3.y * w[13] + a3.z * w[14] + a3.w * w[15];
        }
    }

    // combine row-halves through LDS (reuse g's storage; main loop done with g)
    __syncthreads();
    float* comb = &g[0][0];          // viewed as [GRP][128] (8 KB)
    if (dh == 1) {
        #pragma unroll
        for (int i = 0; i < GRP; i++) comb[i * 128 + col] = acc[i];
    }
    __syncthreads();
    if (dh == 1) return;             // upper half done (after final barrier)
    #pragma unroll
    for (int i = 0; i < GRP; i++) acc[i] += comb[i * 128 + col];

    float hb = bh[h0];
    float wo[4];
    #pragma unroll
    for (int o = 0; o < 4; o++) wo[o] = (o < no) ? Wo[h0 * no + o] : 0.f;

    // epilogue: waves 0-1 (cols 0..127); each wave reduces its 64 cols,
    // both atomicAdd partials -> correct (verified v2 mechanism)
    #pragma unroll
    for (int i = 0; i < GRP; i++) {
        if (i < n) {
            float hv = gelu_exact(acc[i] + hb);
            #pragma unroll
            for (int o = 0; o < 4; o++) {
                if (o < no) {
                    float p = hv * wo[o];
                    #pragma unroll
                    for (int off = 32; off >= 1; off >>= 1) p += __shfl_down(p, off);
                    if (lane == 0) atomicAdd(&pose[bl[i] * 7 + ob + o], p);
                }
            }
        }
    }
}

extern "C" void kernel_launch(void* const* d_in, const int* in_sizes, int n_in,
                              void* d_out, int out_size, void* d_ws, size_t ws_size,
                              hipStream_t stream) {
    const float* dt    = (const float*)d_in[0];
    const float* dr    = (const float*)d_in[1];
    const float* Wsc   = (const float*)d_in[2];
    const float* bsc   = (const float*)d_in[3];
    const float* Wt_h  = (const float*)d_in[4];
    const float* bt_h  = (const float*)d_in[5];
    const float* Wt_o  = (const float*)d_in[6];
    const float* bt_o  = (const float*)d_in[7];
    const float* Wr_h  = (const float*)d_in[8];
    const float* br_h  = (const float*)d_in[9];
    const float* Wr_o  = (const float*)d_in[10];
    const float* br_o  = (const float*)d_in[11];

    float* pose = (float*)d_out;                    // [B,7]
    float* logd = (float*)d_out + BN * 7;           // [B,S]

    int* counts  = (int*)((char*)d_ws + 4096);              // 256 B
    int* lists   = (int*)((char*)d_ws + 8192);              // 256 KB

    hipMemsetAsync(counts, 0, SN * sizeof(int), stream);

    k_scene<<<BN, 256, 0, stream>>>(dt, dr, Wsc, bsc, bt_o, br_o,
                                    logd, pose, counts, lists);
    // max groups = sum ceil(cnt/16) <= (1024 + 64*15)/16 = 124; 124*16 = 1984
    k_expert<<<1984, 256, 0, stream>>>(
        dt, dr, Wt_h, bt_h, Wt_o, Wr_h, br_h, Wr_o, counts, lists, pose);
}

// Round 4
// 299.616 us; speedup vs baseline: 1.0597x; 1.0369x over previous
//
#include <hip/hip_runtime.h>
#include <math.h>

#define BN 1024
#define SN 64
#define DN 256
#define CHN 1024
#define GRP 16

__device__ __forceinline__ float gelu_exact(float x) {
    return 0.5f * x * (1.0f + erff(x * 0.70710678118654752440f));
}

// K1: scene logits + log_softmax + argmax + pose-bias init + scene binning.
// One block per sample b, 256 thr = 4 waves. (unchanged, proven)
__global__ __launch_bounds__(256, 4) void k_scene(
    const float* __restrict__ dt, const float* __restrict__ dr,
    const float* __restrict__ Wsc, const float* __restrict__ bsc,
    const float* __restrict__ bt_o, const float* __restrict__ br_o,
    float* __restrict__ out_logd, float* __restrict__ pose,
    int* __restrict__ counts, int* __restrict__ lists)
{
    int b = blockIdx.x;
    int tid = threadIdx.x;
    int lane = tid & 63;
    int wave = tid >> 6;
    __shared__ float part[SN][65];   // +1 pad: reduction read is 2-way (free)
    __shared__ float logits[SN];

    float4 wt = *(const float4*)&Wsc[4 * lane];
    float4 wr = *(const float4*)&Wsc[DN + 4 * lane];
    const float* pt = dt + (size_t)b * SN * DN + 4 * lane;
    const float* pr = dr + (size_t)b * SN * DN + 4 * lane;
    float bias0 = bsc[0];

    float p[16];
    #pragma unroll 8
    for (int k = 0; k < 16; k++) {
        int s = wave * 16 + k;          // each wave streams a contiguous 16KB chunk
        float4 t4 = *(const float4*)&pt[s * DN];
        float4 r4 = *(const float4*)&pr[s * DN];
        p[k] = t4.x * wt.x + t4.y * wt.y + t4.z * wt.z + t4.w * wt.w
             + r4.x * wr.x + r4.y * wr.y + r4.z * wr.z + r4.w * wr.w;
    }
    #pragma unroll
    for (int k = 0; k < 16; k++) part[wave * 16 + k][lane] = p[k];
    __syncthreads();

    {
        int s = tid >> 2, q = tid & 3;
        float sum = 0.f;
        #pragma unroll
        for (int j = 0; j < 16; j++) sum += part[s][q * 16 + j];
        sum += __shfl_xor(sum, 1);
        sum += __shfl_xor(sum, 2);
        if (q == 0) logits[s] = sum + bias0;
    }
    __syncthreads();

    if (wave == 0) {
        float l = logits[lane];
        float m = l; int idx = lane;
        #pragma unroll
        for (int off = 32; off >= 1; off >>= 1) {
            float om = __shfl_xor(m, off);
            int oidx = __shfl_xor(idx, off);
            if (om > m || (om == m && oidx < idx)) { m = om; idx = oidx; }
        }
        float e = expf(l - m);
        float ssum = e;
        #pragma unroll
        for (int off = 32; off >= 1; off >>= 1) ssum += __shfl_xor(ssum, off);
        float logZ = m + logf(ssum);
        out_logd[b * SN + lane] = l - logZ;
        // fused prep: bin this sample + write pose output biases
        if (lane == 0) {
            int pos = atomicAdd(&counts[idx], 1);
            lists[idx * BN + pos] = b;
        }
        if (lane < 7)
            pose[b * 7 + lane] = (lane < 3) ? bt_o[idx * 3 + lane]
                                            : br_o[idx * 4 + (lane - 3)];
    }
}

// K2 v4: pipe-efficiency rework (v1/v3 were LDS-pipe / VMEM-issue saturated:
// occupancy +50% gave 0% perf).
//  - thread owns 4 ADJACENT cols -> weight loads are global_load_dwordx4
//    (1 KB/wave/inst; 4x fewer VMEM insts than scalar) and each broadcast
//    ds_read_b128 now feeds 16 FMAs (was 4): LDS pipe demand cut 4x.
//  - wave owns a 64-row D-quarter; 4 partials combined via 2-round LDS tree.
//  - item = (group, z, 256-col chunk): 8 items/group, ~745 working blocks.
//  - acc = float4 acc[16] (64 VGPR), all constant-indexed; cap 128 VGPR via
//    __launch_bounds__(256,4).
__global__ __launch_bounds__(256, 4) void k_expert(
    const float* __restrict__ dt, const float* __restrict__ dr,
    const float* __restrict__ Wt_h, const float* __restrict__ bt_h, const float* __restrict__ Wt_o,
    const float* __restrict__ Wr_h, const float* __restrict__ br_h, const float* __restrict__ Wr_o,
    const int* __restrict__ counts, const int* __restrict__ lists,
    float* __restrict__ pose)
{
    __shared__ float g[GRP][DN];      // 16 KB gathered descriptors
    __shared__ float comb[GRP][DN];   // 16 KB combine buffer
    __shared__ int pref[SN + 1];
    __shared__ int bl[GRP];
    int tid = threadIdx.x;
    int lane = tid & 63;
    int wv = tid >> 6;

    // group-count prefix scan (wave 0)
    if (tid < 64) {
        int c = counts[lane];
        int ng = (c + GRP - 1) >> 4;
        #pragma unroll
        for (int off = 1; off < 64; off <<= 1) {
            int v = __shfl_up(ng, off);
            if (lane >= off) ng += v;
        }
        pref[lane + 1] = ng;
        if (lane == 0) pref[0] = 0;
    }
    __syncthreads();

    int q = blockIdx.x;
    if (q >= pref[SN] * 8) return;   // uniform exit

    int s = 0;
    while (pref[s + 1] * 8 <= q) s++;
    int r = q - pref[s] * 8;
    int grp = r >> 3;                // group of up to 16 samples
    int z = (r >> 2) & 1;            // head type (t / rot)
    int chunk = r & 3;               // 256-col chunk of CH

    int cnt = counts[s];
    int base = grp * GRP;
    int n = min(GRP, cnt - base);

    const float* Wh; const float* bh; const float* Wo; const float* descs; int no, ob;
    if (z == 0) {
        Wh = Wt_h + (size_t)s * DN * CHN; bh = bt_h + s * CHN;
        Wo = Wt_o + (size_t)s * CHN * 3;  descs = dt; no = 3; ob = 0;
    } else {
        Wh = Wr_h + (size_t)s * DN * CHN; bh = br_h + s * CHN;
        Wo = Wr_o + (size_t)s * CHN * 4;  descs = dr; no = 4; ob = 3;
    }

    // gather: 16 rows x 256 floats, one row per 256-thread pass (coalesced)
    #pragma unroll 4
    for (int i = 0; i < GRP; i++) {
        int bi = 0; float v = 0.f;
        if (i < n) {
            bi = lists[s * BN + base + i];
            v = descs[(size_t)bi * SN * DN + s * DN + tid];
        }
        g[i][tid] = v;
        if (tid == 0) bl[i] = bi;
    }
    __syncthreads();

    int d0 = wv << 6;                // wave owns rows d0..d0+63
    int h0 = (chunk << 8) + lane * 4; // 4 adjacent hidden cols
    const float* wp = Wh + (size_t)d0 * CHN + h0;

    float4 acc[GRP];
    #pragma unroll
    for (int i = 0; i < GRP; i++) acc[i] = make_float4(0.f, 0.f, 0.f, 0.f);

    // 16 steps of 4 rows: 4x dwordx4 weight loads, 16 broadcast ds_read_b128,
    // 256 FMA per step
    #pragma unroll 2
    for (int st = 0; st < 16; st++) {
        int db = st * 4;
        float4 w0 = *(const float4*)&wp[(size_t)(db + 0) * CHN];
        float4 w1 = *(const float4*)&wp[(size_t)(db + 1) * CHN];
        float4 w2 = *(const float4*)&wp[(size_t)(db + 2) * CHN];
        float4 w3 = *(const float4*)&wp[(size_t)(db + 3) * CHN];
        #pragma unroll
        for (int i = 0; i < GRP; i++) {
            float4 gv = *(const float4*)&g[i][d0 + db];  // wave-uniform broadcast
            acc[i].x += gv.x * w0.x + gv.y * w1.x + gv.z * w2.x + gv.w * w3.x;
            acc[i].y += gv.x * w0.y + gv.y * w1.y + gv.z * w2.y + gv.w * w3.y;
            acc[i].z += gv.x * w0.z + gv.y * w1.z + gv.z * w2.z + gv.w * w3.z;
            acc[i].w += gv.x * w0.w + gv.y * w1.w + gv.z * w2.w + gv.w * w3.w;
        }
    }

    // combine quarters: wv2->g, wv3->comb; wv0+=g, wv1+=comb; wv1->g; wv0+=g
    __syncthreads();                 // all waves done reading g
    if (wv == 2) {
        #pragma unroll
        for (int i = 0; i < GRP; i++) *(float4*)&g[i][lane * 4] = acc[i];
    } else if (wv == 3) {
        #pragma unroll
        for (int i = 0; i < GRP; i++) *(float4*)&comb[i][lane * 4] = acc[i];
    }
    __syncthreads();
    if (wv == 0) {
        #pragma unroll
        for (int i = 0; i < GRP; i++) {
            float4 v = *(const float4*)&g[i][lane * 4];
            acc[i].x += v.x; acc[i].y += v.y; acc[i].z += v.z; acc[i].w += v.w;
        }
    } else if (wv == 1) {
        #pragma unroll
        for (int i = 0; i < GRP; i++) {
            float4 v = *(const float4*)&comb[i][lane * 4];
            acc[i].x += v.x; acc[i].y += v.y; acc[i].z += v.z; acc[i].w += v.w;
        }
    }
    __syncthreads();
    if (wv == 1) {
        #pragma unroll
        for (int i = 0; i < GRP; i++) *(float4*)&g[i][lane * 4] = acc[i];
    }
    __syncthreads();
    if (wv != 0) return;             // all barriers passed; wave 0 finishes
    #pragma unroll
    for (int i = 0; i < GRP; i++) {
        float4 v = *(const float4*)&g[i][lane * 4];
        acc[i].x += v.x; acc[i].y += v.y; acc[i].z += v.z; acc[i].w += v.w;
    }

    float4 hb4 = *(const float4*)&bh[h0];
    float wo[4][4];                  // wo[o][c] = Wo[(h0+c)*no + o]
    #pragma unroll
    for (int c = 0; c < 4; c++)
        #pragma unroll
        for (int o = 0; o < 4; o++)
            wo[o][c] = (o < no) ? Wo[(size_t)(h0 + c) * no + o] : 0.f;

    #pragma unroll
    for (int i = 0; i < GRP; i++) {
        if (i < n) {
            float hx = gelu_exact(acc[i].x + hb4.x);
            float hy = gelu_exact(acc[i].y + hb4.y);
            float hz = gelu_exact(acc[i].z + hb4.z);
            float hw = gelu_exact(acc[i].w + hb4.w);
            #pragma unroll
            for (int o = 0; o < 4; o++) {
                if (o < no) {
                    float p = hx * wo[o][0] + hy * wo[o][1]
                            + hz * wo[o][2] + hw * wo[o][3];
                    #pragma unroll
                    for (int off = 32; off >= 1; off >>= 1) p += __shfl_down(p, off);
                    if (lane == 0) atomicAdd(&pose[bl[i] * 7 + ob + o], p);
                }
            }
        }
    }
}

extern "C" void kernel_launch(void* const* d_in, const int* in_sizes, int n_in,
                              void* d_out, int out_size, void* d_ws, size_t ws_size,
                              hipStream_t stream) {
    const float* dt    = (const float*)d_in[0];
    const float* dr    = (const float*)d_in[1];
    const float* Wsc   = (const float*)d_in[2];
    const float* bsc   = (const float*)d_in[3];
    const float* Wt_h  = (const float*)d_in[4];
    const float* bt_h  = (const float*)d_in[5];
    const float* Wt_o  = (const float*)d_in[6];
    const float* bt_o  = (const float*)d_in[7];
    const float* Wr_h  = (const float*)d_in[8];
    const float* br_h  = (const float*)d_in[9];
    const float* Wr_o  = (const float*)d_in[10];
    const float* br_o  = (const float*)d_in[11];

    float* pose = (float*)d_out;                    // [B,7]
    float* logd = (float*)d_out + BN * 7;           // [B,S]

    int* counts  = (int*)((char*)d_ws + 4096);              // 256 B
    int* lists   = (int*)((char*)d_ws + 8192);              // 256 KB

    hipMemsetAsync(counts, 0, SN * sizeof(int), stream);

    k_scene<<<BN, 256, 0, stream>>>(dt, dr, Wsc, bsc, bt_o, br_o,
                                    logd, pose, counts, lists);
    // max groups = sum ceil(cnt/16) <= (1024 + 64*15)/16 = 124; 124*8 = 992
    k_expert<<<992, 256, 0, stream>>>(
        dt, dr, Wt_h, bt_h, Wt_o, Wr_h, br_h, Wr_o, counts, lists, pose);
}